// Round 1
// baseline (141.336 us; speedup 1.0000x reference)
//
#include <hip/hip_runtime.h>

// RBFN fused kernel: out = sqrt(1 + max(|x|^2 + |c|^2 - 2 x.c, 0)) @ W
// d=8192 rows, n=128 feat, N=8192 centres, l=64 out cols. All fp32 in/out.
// Strategy: flash-style fusion, bf16 MFMA 16x16x32 (verified layouts only),
// K augmented 128->160 so the MFMA computes 1+x2+c2-2x.c directly.

typedef __attribute__((ext_vector_type(8))) short bf16x8;   // 8 bf16 = 4 VGPRs
typedef __attribute__((ext_vector_type(4))) float f32x4;    // MFMA C/D

#define N_FEAT 128
#define N_CENT 8192
#define L_OUT  64
#define BM     256            // rows per block (4 waves x 64-row strips)
#define BN     32             // centres per iteration
#define KC     5              // k-chunks of 32 (128 feat + 32 aug)
#define LDK    168            // stage row stride (bf16), 336B = 16B-aligned
#define LDP    40             // phi/W row stride (bf16), 80B = 16B-aligned
#define NSPLIT 16             // centre-dim split (atomicAdd combine)
#define ITERS  ((N_CENT / NSPLIT) / BN)   // 16

__device__ __forceinline__ unsigned short f2bf(float f) {
    // round-to-nearest-even bf16 (inputs finite)
    unsigned int u = __builtin_bit_cast(unsigned int, f);
    u += 0x7FFFu + ((u >> 16) & 1u);
    return (unsigned short)(u >> 16);
}

// Stage 32 rows x 128 cols fp32 -> bf16 LDS with augmentation columns.
// 8 threads per row, 16 cols each. scale applied to stored values (-2 for x).
// aug cols: isX ? [x2+1, 1, 0...] : [1, c2, 0...]; sumsq computed on raw fp32.
__device__ __forceinline__ void stage_rows(const float* __restrict__ src,
                                           float scale, int isX,
                                           int sr, int sq,
                                           unsigned short (*buf)[LDK]) {
    const float* g = src + sq * 16;
    float ss = 0.f;
    #pragma unroll
    for (int i = 0; i < 4; ++i) {
        f32x4 t = *(const f32x4*)(g + i * 4);
        ss += t.x * t.x + t.y * t.y + t.z * t.z + t.w * t.w;
        ushort4 b = make_ushort4(f2bf(scale * t.x), f2bf(scale * t.y),
                                 f2bf(scale * t.z), f2bf(scale * t.w));
        *(ushort4*)&buf[sr][sq * 16 + i * 4] = b;
    }
    // reduce sumsq across the 8 threads of this row (contiguous lanes)
    ss += __shfl_xor(ss, 1);
    ss += __shfl_xor(ss, 2);
    ss += __shfl_xor(ss, 4);
    unsigned short a0 = isX ? f2bf(ss + 1.0f) : f2bf(1.0f);
    unsigned short a1 = isX ? f2bf(1.0f)      : f2bf(ss);
    ushort4 z = (sq == 0) ? make_ushort4(a0, a1, 0, 0)
                          : make_ushort4(0, 0, 0, 0);
    *(ushort4*)&buf[sr][128 + sq * 4] = z;   // 8 threads cover cols 128..159
}

__global__ __launch_bounds__(256, 2) void rbf_fused(
    const float* __restrict__ xs, const float* __restrict__ centre,
    const float* __restrict__ weight, float* __restrict__ out) {

    __shared__ __align__(16) unsigned short sStage[32][LDK];  // X piece / centre chunk
    __shared__ __align__(16) unsigned short sW[L_OUT][LDP];   // W chunk, transposed [l][k]
    __shared__ __align__(16) unsigned short sPhi[BM][LDP];    // phi strips, per-wave

    const int tid  = threadIdx.x;
    const int w    = tid >> 6;
    const int lane = tid & 63;
    const int quad = lane >> 4;
    const int n16  = lane & 15;

    const int mb = blockIdx.x >> 4;          // 0..31 row block
    const int sb = blockIdx.x & (NSPLIT - 1);
    const int rowBase  = mb * BM;
    const int centBase = sb * (N_CENT / NSPLIT);

    const int sr = tid >> 3;   // staging row 0..31
    const int sq = tid & 7;    // staging col-group 0..7

    bf16x8 aF[4][KC];          // register-resident A fragments (this wave's 64 rows)
    f32x4  oAcc[4][4];         // out accumulator: 4 m-tiles x 4 l-tiles
    #pragma unroll
    for (int mt = 0; mt < 4; ++mt)
        #pragma unroll
        for (int lt = 0; lt < 4; ++lt)
            oAcc[mt][lt] = (f32x4){0.f, 0.f, 0.f, 0.f};

    // ---- prologue: stage X in 8 pieces of 32 rows; owner wave grabs A-frags
    for (int p = 0; p < 8; ++p) {
        __syncthreads();
        stage_rows(xs + (size_t)(rowBase + p * 32 + sr) * N_FEAT, -2.0f, 1,
                   sr, sq, sStage);
        __syncthreads();
        if (w == (p >> 1)) {
            const int half = p & 1;   // which 32-row half of this wave's strip
            #pragma unroll
            for (int m2 = 0; m2 < 2; ++m2)
                #pragma unroll
                for (int kc = 0; kc < KC; ++kc)
                    aF[half * 2 + m2][kc] =
                        *(const bf16x8*)&sStage[m2 * 16 + n16][kc * 32 + quad * 8];
        }
    }

    // ---- main loop over centre chunks
    for (int it = 0; it < ITERS; ++it) {
        const int n0 = centBase + it * BN;
        __syncthreads();   // protect sStage/sW from previous iteration's readers
        stage_rows(centre + (size_t)(n0 + sr) * N_FEAT, 1.0f, 0, sr, sq, sStage);
        {   // stage W chunk transposed: sW[l][k] = W[n0+k][l]
            const int rr  = tid >> 3;         // 0..31 chunk row (centre)
            const int cc0 = (tid & 7) * 8;    // 8 l-cols
            const float* gw = weight + (size_t)(n0 + rr) * L_OUT + cc0;
            f32x4 t0 = *(const f32x4*)gw;
            f32x4 t1 = *(const f32x4*)(gw + 4);
            sW[cc0 + 0][rr] = f2bf(t0.x); sW[cc0 + 1][rr] = f2bf(t0.y);
            sW[cc0 + 2][rr] = f2bf(t0.z); sW[cc0 + 3][rr] = f2bf(t0.w);
            sW[cc0 + 4][rr] = f2bf(t1.x); sW[cc0 + 5][rr] = f2bf(t1.y);
            sW[cc0 + 6][rr] = f2bf(t1.z); sW[cc0 + 7][rr] = f2bf(t1.w);
        }
        __syncthreads();

        // GEMM1: S[64 x 32] per wave = 1 + x2 + c2 - 2 x.c  (via aug-K)
        f32x4 sAcc[4][2];
        #pragma unroll
        for (int mt = 0; mt < 4; ++mt)
            #pragma unroll
            for (int ct = 0; ct < 2; ++ct)
                sAcc[mt][ct] = (f32x4){0.f, 0.f, 0.f, 0.f};
        #pragma unroll
        for (int kc = 0; kc < KC; ++kc) {
            #pragma unroll
            for (int ct = 0; ct < 2; ++ct) {
                bf16x8 bF = *(const bf16x8*)&sStage[ct * 16 + n16][kc * 32 + quad * 8];
                #pragma unroll
                for (int mt = 0; mt < 4; ++mt)
                    sAcc[mt][ct] = __builtin_amdgcn_mfma_f32_16x16x32_bf16(
                        aF[mt][kc], bF, sAcc[mt][ct], 0, 0, 0);
            }
        }

        // phi = sqrt(max(t, 1)); write to this wave's own LDS strip (no barrier:
        // each wave reads back exactly what it wrote)
        #pragma unroll
        for (int mt = 0; mt < 4; ++mt)
            #pragma unroll
            for (int ct = 0; ct < 2; ++ct)
                #pragma unroll
                for (int r = 0; r < 4; ++r) {
                    float t = sAcc[mt][ct][r];
                    t = fmaxf(t, 1.0f);
                    float ph = __builtin_amdgcn_sqrtf(t);
                    sPhi[64 * w + mt * 16 + quad * 4 + r][ct * 16 + n16] = f2bf(ph);
                }

        // GEMM2: oAcc += phi[64 x 32] @ W[32 x 64]   (K = 32 -> one chunk)
        bf16x8 pF[4];
        #pragma unroll
        for (int mt = 0; mt < 4; ++mt)
            pF[mt] = *(const bf16x8*)&sPhi[64 * w + mt * 16 + n16][quad * 8];
        #pragma unroll
        for (int lt = 0; lt < 4; ++lt) {
            bf16x8 wF = *(const bf16x8*)&sW[lt * 16 + n16][quad * 8];
            #pragma unroll
            for (int mt = 0; mt < 4; ++mt)
                oAcc[mt][lt] = __builtin_amdgcn_mfma_f32_16x16x32_bf16(
                    pF[mt], wF, oAcc[mt][lt], 0, 0, 0);
        }
    }

    // ---- epilogue: combine the NSPLIT partial sums with device-scope atomics
    float* ob = out + (size_t)(rowBase + 64 * w) * L_OUT;
    #pragma unroll
    for (int mt = 0; mt < 4; ++mt)
        #pragma unroll
        for (int lt = 0; lt < 4; ++lt)
            #pragma unroll
            for (int r = 0; r < 4; ++r) {
                int row = mt * 16 + quad * 4 + r;
                int col = lt * 16 + n16;
                atomicAdd(&ob[row * L_OUT + col], oAcc[mt][lt][r]);
            }
}

extern "C" void kernel_launch(void* const* d_in, const int* in_sizes, int n_in,
                              void* d_out, int out_size, void* d_ws, size_t ws_size,
                              hipStream_t stream) {
    (void)in_sizes; (void)n_in; (void)d_ws; (void)ws_size; (void)out_size;
    const float* xs     = (const float*)d_in[0];
    const float* centre = (const float*)d_in[1];
    const float* weight = (const float*)d_in[2];
    float* out = (float*)d_out;

    hipMemsetAsync(d_out, 0, (size_t)8192 * L_OUT * sizeof(float), stream);
    rbf_fused<<<dim3(32 * NSPLIT), dim3(256), 0, stream>>>(xs, centre, weight, out);
}